// Round 4
// baseline (467.633 us; speedup 1.0000x reference)
//
#include <hip/hip_runtime.h>

#define S_LEN 2048
#define HID_DIM 3072
#define NH 32
#define NKV 8
#define HD 96
#define QKV_OUT 4608  // NH*HD + 2*NKV*HD

typedef __attribute__((ext_vector_type(8))) short short8;
typedef __attribute__((ext_vector_type(4))) float floatx4;

// ---------- helpers ----------
__device__ __forceinline__ unsigned short f2b(float f) {
    unsigned int u = __float_as_uint(f);
    u = (u + 0x7FFFu + ((u >> 16) & 1u)) >> 16;   // RNE
    return (unsigned short)u;
}
__device__ __forceinline__ float b2f(unsigned short h) {
    return __uint_as_float(((unsigned int)h) << 16);
}
__device__ __forceinline__ void async_ld16(const void* g, void* l) {
    __builtin_amdgcn_global_load_lds((const __attribute__((address_space(1))) void*)g,
                                     (__attribute__((address_space(3))) void*)l, 16, 0, 0);
}
__device__ __forceinline__ float fast_exp2(float x) {
#if __has_builtin(__builtin_amdgcn_exp2f)
    return __builtin_amdgcn_exp2f(x);   // v_exp_f32
#else
    return exp2f(x);
#endif
}
__device__ __forceinline__ void store_out(float* C, size_t i, float v) { C[i] = v; }
__device__ __forceinline__ void store_out(unsigned short* C, size_t i, float v) { C[i] = f2b(v); }

// ---------- f32 -> bf16 convert, 3 tensors in one launch ----------
__global__ void cvt3_f32_bf16(const float4* __restrict__ a, int na,
                              const float4* __restrict__ b, int nb,
                              const float4* __restrict__ c, int nc,
                              ushort4* __restrict__ oa, ushort4* __restrict__ ob,
                              ushort4* __restrict__ oc) {
    int i = blockIdx.x * 256 + threadIdx.x;
    const float4* src;
    ushort4* dst;
    int j = i;
    if (j < na) { src = a; dst = oa; }
    else {
        j -= na;
        if (j < nb) { src = b; dst = ob; }
        else {
            j -= nb;
            if (j >= nc) return;
            src = c; dst = oc;
        }
    }
    float4 v = src[j];
    ushort4 o;
    o.x = f2b(v.x); o.y = f2b(v.y); o.z = f2b(v.z); o.w = f2b(v.w);
    dst[j] = o;
}

// ---------- GEMM: C[M][N] = A[M][K] * B[N][K]^T  (bf16 in, OUT out) ----------
// 128x128 tile, BK=64, global_load_lds width 16. LDS tiles are stored in MFMA
// *fragment order* (permutation carried on the per-lane global address), so
// every fragment read is ds_read_b128 at base + lane*16 -> conflict-free
// (2-way bank alias only, which is free per m136).
template <typename OUT>
__global__ void gemm_bt(const unsigned short* __restrict__ A,
                        const unsigned short* __restrict__ B,
                        OUT* __restrict__ C, int M, int N, int K) {
    __shared__ unsigned short As[16 * 512];   // slot s = x*2+kkb: rows x*16..+15, k-chunk kkb*32
    __shared__ unsigned short Bs[16 * 512];
    const int t = threadIdx.x;
    const int w = t >> 6;
    const int l = t & 63;
    const int lane15 = l & 15;
    const int quad = l >> 4;
    const int row0 = blockIdx.y * 128;
    const int col0 = blockIdx.x * 128;
    const int wm = (w >> 1) * 64;
    const int wn = (w & 1) * 64;

    // per-lane staging offsets (k-tile invariant); slot s = w*4+j
    int off[4];
#pragma unroll
    for (int j = 0; j < 4; ++j) {
        int s = w * 4 + j;
        int x = s >> 1, kkb = s & 1;
        off[j] = (x * 16 + lane15) * K + kkb * 32 + quad * 8;
    }
    const unsigned short* Arow = A + (size_t)row0 * K;
    const unsigned short* Brow = B + (size_t)col0 * K;

    const floatx4 vzero = {0.f, 0.f, 0.f, 0.f};
    floatx4 acc[4][4];
#pragma unroll
    for (int i = 0; i < 4; ++i)
#pragma unroll
        for (int j = 0; j < 4; ++j) acc[i][j] = vzero;

    const int xA = wm >> 4, xB = wn >> 4;
    for (int k0 = 0; k0 < K; k0 += 64) {
        __syncthreads();
#pragma unroll
        for (int j = 0; j < 4; ++j) {
            int s = w * 4 + j;
            async_ld16(Arow + k0 + off[j], As + s * 512 + l * 8);
            async_ld16(Brow + k0 + off[j], Bs + s * 512 + l * 8);
        }
        __syncthreads();
#pragma unroll
        for (int kkb = 0; kkb < 2; ++kkb) {
            short8 af[4], bfr[4];
#pragma unroll
            for (int mi = 0; mi < 4; ++mi)
                af[mi] = *(const short8*)(As + ((xA + mi) * 2 + kkb) * 512 + l * 8);
#pragma unroll
            for (int ni = 0; ni < 4; ++ni)
                bfr[ni] = *(const short8*)(Bs + ((xB + ni) * 2 + kkb) * 512 + l * 8);
#pragma unroll
            for (int mi = 0; mi < 4; ++mi)
#pragma unroll
                for (int ni = 0; ni < 4; ++ni)
                    acc[mi][ni] = __builtin_amdgcn_mfma_f32_16x16x32_bf16(af[mi], bfr[ni], acc[mi][ni], 0, 0, 0);
        }
    }
#pragma unroll
    for (int mi = 0; mi < 4; ++mi)
#pragma unroll
        for (int ni = 0; ni < 4; ++ni)
#pragma unroll
            for (int r = 0; r < 4; ++r) {
                int m = row0 + wm + mi * 16 + quad * 4 + r;
                int n = col0 + wn + ni * 16 + lane15;
                store_out(C, (size_t)m * N + n, acc[mi][ni][r]);
            }
}

// ---------- RoPE + split qkv -> Q [NH][S][HD] (pre-scaled), K, V [NKV][S][HD] ----------
// Q is scaled by 1/sqrt(HD) * log2(e) so attention scores land in exp2 domain.
__global__ void rope_split(const unsigned short* __restrict__ qkv,
                           unsigned short* __restrict__ Qd,
                           unsigned short* __restrict__ Kd,
                           unsigned short* __restrict__ Vd) {
    const int s = blockIdx.x;
    const int t = threadIdx.x;
    const unsigned short* row = qkv + (size_t)s * QKV_OUT;
    const float L2T_48 = 0.2768273412406135f;   // log2(10000)/48
    const float SCALE2 = 0.14724444f;           // (1/sqrt(96)) * log2(e)

    for (int i = t; i < NH * 48; i += 256) {
        int h = i / 48, d = i - (i / 48) * 48;
        float f = (float)s * exp2f(-(float)d * L2T_48);
        float sn, cs;
        sincosf(f, &sn, &cs);
        float q1 = b2f(row[h * 96 + d]);
        float q2 = b2f(row[h * 96 + d + 48]);
        size_t base = ((size_t)h * S_LEN + s) * HD;
        Qd[base + d] = f2b((q1 * cs - q2 * sn) * SCALE2);
        Qd[base + d + 48] = f2b((q2 * cs + q1 * sn) * SCALE2);
    }
    for (int i = t; i < NKV * 48; i += 256) {
        int h = i / 48, d = i - (i / 48) * 48;
        float f = (float)s * exp2f(-(float)d * L2T_48);
        float sn, cs;
        sincosf(f, &sn, &cs);
        float k1 = b2f(row[3072 + h * 96 + d]);
        float k2 = b2f(row[3072 + h * 96 + d + 48]);
        size_t base = ((size_t)h * S_LEN + s) * HD;
        Kd[base + d] = f2b(k1 * cs - k2 * sn);
        Kd[base + d + 48] = f2b(k2 * cs + k1 * sn);
    }
    for (int i = t; i < NKV * HD; i += 256) {
        int h = i / 96, d = i - (i / 96) * 96;
        Vd[((size_t)h * S_LEN + s) * HD + d] = row[3840 + i];
    }
}

// ---------- V [NKV][S][HD] -> Vt [NKV][HD][S], LDS-tiled ----------
__global__ void transpose_v(const unsigned short* __restrict__ V,
                            unsigned short* __restrict__ Vt) {
    __shared__ unsigned short T[96][72];   // +pad vs 64 to break conflicts
    const int kvh = blockIdx.x >> 5;
    const int s0 = (blockIdx.x & 31) * 64;
    const int t = threadIdx.x;
#pragma unroll
    for (int it = 0; it < 3; ++it) {
        int c = it * 256 + t;
        int r = c / 12, c8 = c - r * 12;
        short8 v = *(const short8*)(V + ((size_t)kvh * S_LEN + s0 + r) * HD + c8 * 8);
#pragma unroll
        for (int j = 0; j < 8; ++j) T[c8 * 8 + j][r] = (unsigned short)v[j];
    }
    __syncthreads();
#pragma unroll
    for (int it = 0; it < 3; ++it) {
        int c = it * 256 + t;
        int d = c >> 3, c8 = c & 7;
        short8 v;
#pragma unroll
        for (int j = 0; j < 8; ++j) v[j] = (short)T[d][c8 * 8 + j];
        *(short8*)(Vt + ((size_t)kvh * HD + d) * S_LEN + s0 + c8 * 8) = v;
    }
}

// ---------- Flash attention, fixed-max (shift-invariant) softmax ----------
#define ATTN_M0 8.0f
__global__ __launch_bounds__(256) void attn_fwd(const unsigned short* __restrict__ Q,
                                                const unsigned short* __restrict__ K,
                                                const unsigned short* __restrict__ Vt,
                                                unsigned short* __restrict__ O) {
    __shared__ unsigned short Qs[4 * 3 * 512];   // [w][kkb][lane*8]
    __shared__ unsigned short Ks[12 * 512];      // [kkb*4+ct][lane*8]
    __shared__ unsigned short Vs[12 * 512];      // [kb2*6+nt][lane*8]
    __shared__ unsigned short Ps[4][16 * 72];    // per-wave P, stride 72
    const int h = blockIdx.x;
    const int qt = (int)gridDim.y - 1 - blockIdx.y;  // LPT: longest first
    const int kvh = h >> 2;                          // N_REP = 4
    const int q0 = qt * 64;
    const int t = threadIdx.x, w = t >> 6, l = t & 63;
    const int lane15 = l & 15, quad = l >> 4;
    unsigned short* Pw = Ps[w];

    const unsigned short* Qg = Q + ((size_t)h * S_LEN + q0) * HD;
#pragma unroll
    for (int kkb = 0; kkb < 3; ++kkb)
        async_ld16(Qg + (w * 16 + lane15) * HD + kkb * 32 + quad * 8,
                   Qs + (w * 3 + kkb) * 512 + l * 8);

    int koff[3], voff0[3];
    long vofS[3];
#pragma unroll
    for (int j = 0; j < 3; ++j) {
        int c = w * 3 + j;
        int ct = c & 3, kkb = c >> 2;
        koff[j] = (ct * 16 + lane15) * HD + kkb * 32 + quad * 8;
        int nt = c % 6, kb2 = c / 6;
        vofS[j] = (long)(nt * 16 + lane15) * S_LEN + kb2 * 32 + quad * 8;
        voff0[j] = c * 512 + l * 8;
    }

    const floatx4 vzero = {0.f, 0.f, 0.f, 0.f};
    floatx4 accO[6];
#pragma unroll
    for (int nt = 0; nt < 6; ++nt) accO[nt] = vzero;
    float lsum[4] = {0.f, 0.f, 0.f, 0.f};

    const unsigned short* Kg = K + (size_t)kvh * S_LEN * HD;
    const unsigned short* Vg = Vt + (size_t)kvh * HD * S_LEN;
    const int qrow0 = q0 + w * 16 + quad * 4;

    for (int kt = 0; kt <= qt; ++kt) {
        const int k0 = kt * 64;
        __syncthreads();  // prev-iter readers done with Ks/Vs
#pragma unroll
        for (int j = 0; j < 3; ++j) {
            int c = w * 3 + j;
            async_ld16(Kg + (size_t)k0 * HD + koff[j], Ks + c * 512 + l * 8);
            async_ld16(Vg + k0 + vofS[j], Vs + voff0[j]);
        }
        __syncthreads();  // staging visible to all waves

        floatx4 accS[4];
#pragma unroll
        for (int ct = 0; ct < 4; ++ct) accS[ct] = vzero;
#pragma unroll
        for (int kkb = 0; kkb < 3; ++kkb) {
            short8 aq = *(const short8*)(Qs + (w * 3 + kkb) * 512 + l * 8);
#pragma unroll
            for (int ct = 0; ct < 4; ++ct) {
                short8 bk = *(const short8*)(Ks + (kkb * 4 + ct) * 512 + l * 8);
                accS[ct] = __builtin_amdgcn_mfma_f32_16x16x32_bf16(aq, bk, accS[ct], 0, 0, 0);
            }
        }

        if (kt < qt) {
#pragma unroll
            for (int ct = 0; ct < 4; ++ct)
#pragma unroll
                for (int r = 0; r < 4; ++r) {
                    float p = fast_exp2(accS[ct][r] - ATTN_M0);
                    lsum[r] += p;
                    Pw[(quad * 4 + r) * 72 + ct * 16 + lane15] = f2b(p);
                }
        } else {
#pragma unroll
            for (int ct = 0; ct < 4; ++ct) {
                int kcol = k0 + ct * 16 + lane15;
#pragma unroll
                for (int r = 0; r < 4; ++r) {
                    float s = (kcol <= qrow0 + r) ? accS[ct][r] - ATTN_M0 : -1.0e30f;
                    float p = fast_exp2(s);
                    lsum[r] += p;
                    Pw[(quad * 4 + r) * 72 + ct * 16 + lane15] = f2b(p);
                }
            }
        }

#pragma unroll
        for (int kb2 = 0; kb2 < 2; ++kb2) {
            short8 ap = *(const short8*)(Pw + lane15 * 72 + kb2 * 32 + quad * 8);
#pragma unroll
            for (int nt = 0; nt < 6; ++nt) {
                short8 bv = *(const short8*)(Vs + (kb2 * 6 + nt) * 512 + l * 8);
                accO[nt] = __builtin_amdgcn_mfma_f32_16x16x32_bf16(ap, bv, accO[nt], 0, 0, 0);
            }
        }
    }

    for (int off = 1; off < 16; off <<= 1)
#pragma unroll
        for (int r = 0; r < 4; ++r) lsum[r] += __shfl_xor(lsum[r], off, 64);
    float inv[4];
#pragma unroll
    for (int r = 0; r < 4; ++r) inv[r] = 1.f / lsum[r];
    const int srow0 = q0 + w * 16 + quad * 4;
#pragma unroll
    for (int nt = 0; nt < 6; ++nt)
#pragma unroll
        for (int r = 0; r < 4; ++r)
            O[(size_t)(srow0 + r) * HID_DIM + h * HD + nt * 16 + lane15] = f2b(accO[nt][r] * inv[r]);
}

// ---------- launcher ----------
extern "C" void kernel_launch(void* const* d_in, const int* in_sizes, int n_in,
                              void* d_out, int out_size, void* d_ws, size_t ws_size,
                              hipStream_t stream) {
    const float* hidden = (const float*)d_in[0];
    const float* qkv_w = (const float*)d_in[3];
    const float* o_w = (const float*)d_in[4];
    float* out = (float*)d_out;

    unsigned short* Xb = (unsigned short*)d_ws;                 // [2048][3072] bf16
    unsigned short* Wq = Xb + (size_t)S_LEN * HID_DIM;          // [4608][3072]
    unsigned short* Wo = Wq + (size_t)QKV_OUT * HID_DIM;        // [3072][3072]
    unsigned short* QKVb = Wo + (size_t)HID_DIM * HID_DIM;      // [2048][4608]
    unsigned short* Qb = QKVb + (size_t)S_LEN * QKV_OUT;        // [32][2048][96]
    unsigned short* Kb = Qb + (size_t)NH * S_LEN * HD;          // [8][2048][96]
    unsigned short* Vb = Kb + (size_t)NKV * S_LEN * HD;         // [8][2048][96]
    unsigned short* Ab = Vb + (size_t)NKV * S_LEN * HD;         // [2048][3072]
    unsigned short* Vtb = QKVb;  // V^T [8][96][2048]; QKVb dead after rope_split

    int n1 = S_LEN * HID_DIM / 4, n2 = QKV_OUT * HID_DIM / 4, n3 = HID_DIM * HID_DIM / 4;
    int ntot = n1 + n2 + n3;
    cvt3_f32_bf16<<<(ntot + 255) / 256, 256, 0, stream>>>(
        (const float4*)hidden, n1, (const float4*)qkv_w, n2, (const float4*)o_w, n3,
        (ushort4*)Xb, (ushort4*)Wq, (ushort4*)Wo);

    gemm_bt<unsigned short><<<dim3(QKV_OUT / 128, S_LEN / 128), 256, 0, stream>>>(
        Xb, Wq, QKVb, S_LEN, QKV_OUT, HID_DIM);
    rope_split<<<S_LEN, 256, 0, stream>>>(QKVb, Qb, Kb, Vb);
    transpose_v<<<NKV * (S_LEN / 64), 256, 0, stream>>>(Vb, Vtb);
    attn_fwd<<<dim3(NH, S_LEN / 64), 256, 0, stream>>>(Qb, Kb, Vtb, Ab);
    gemm_bt<float><<<dim3(HID_DIM / 128, S_LEN / 128), 256, 0, stream>>>(
        Ab, Wo, out, S_LEN, HID_DIM, HID_DIM);
}

// Round 5
// 375.752 us; speedup vs baseline: 1.2445x; 1.2445x over previous
//
#include <hip/hip_runtime.h>

#define S_LEN 2048
#define HID_DIM 3072
#define NH 32
#define NKV 8
#define HD 96
#define QKV_OUT 4608  // NH*HD + 2*NKV*HD

typedef __attribute__((ext_vector_type(8))) short short8;
typedef __attribute__((ext_vector_type(4))) float floatx4;

// ---------- helpers ----------
__device__ __forceinline__ unsigned short f2b(float f) {
    unsigned int u = __float_as_uint(f);
    u = (u + 0x7FFFu + ((u >> 16) & 1u)) >> 16;   // RNE
    return (unsigned short)u;
}
__device__ __forceinline__ float b2f(unsigned short h) {
    return __uint_as_float(((unsigned int)h) << 16);
}
__device__ __forceinline__ void async_ld16(const void* g, void* l) {
    __builtin_amdgcn_global_load_lds((const __attribute__((address_space(1))) void*)g,
                                     (__attribute__((address_space(3))) void*)l, 16, 0, 0);
}
__device__ __forceinline__ float fast_exp2(float x) {
#if __has_builtin(__builtin_amdgcn_exp2f)
    return __builtin_amdgcn_exp2f(x);   // v_exp_f32
#else
    return exp2f(x);
#endif
}
__device__ __forceinline__ void store_out(float* C, size_t i, float v) { C[i] = v; }
__device__ __forceinline__ void store_out(unsigned short* C, size_t i, float v) { C[i] = f2b(v); }

// ===================== MFMA-fragment-tiled global format =====================
// Matrix [R][K] (K multiple of 32, R multiple of 16) stored as 512-short blocks:
//   blk = (r>>4)*(K>>5) + (k>>5)
//   pos = ((k&31)>>3)*128 + (r&15)*8 + (k&7)
// Block content == exact wave lane order for MFMA A/B fragments (lane l = q*16+i
// holds elements (i, q*8+j)), so global->LDS staging is ONE contiguous 1KB
// async_ld16 per wave AND LDS reads are ds_read_b128 at base+lane*16 (conflict-
// free). Fixes R4's 64B-segment global regression while keeping 0 conflicts.

// ---------- f32 row-major -> bf16 tiled, 3 tensors (all K=3072) ----------
__global__ void cvt3_tiled(const float4* __restrict__ a, int na4,
                           const float4* __restrict__ b, int nb4,
                           const float4* __restrict__ c, int nc4,
                           unsigned short* __restrict__ oa,
                           unsigned short* __restrict__ ob,
                           unsigned short* __restrict__ oc) {
    int i = blockIdx.x * 256 + threadIdx.x;
    const float4* src;
    unsigned short* dst;
    int j = i;
    if (j < na4) { src = a; dst = oa; }
    else {
        j -= na4;
        if (j < nb4) { src = b; dst = ob; }
        else {
            j -= nb4;
            if (j >= nc4) return;
            src = c; dst = oc;
        }
    }
    float4 v = src[j];
    int off = j * 4;               // element offset in row-major [R][3072]
    int r = off / HID_DIM;
    int k = off - r * HID_DIM;
    size_t blk = (size_t)(r >> 4) * (HID_DIM >> 5) + (k >> 5);
    int pos = ((k & 31) >> 3) * 128 + (r & 15) * 8 + (k & 7);   // k&7 in {0,4}
    ushort4 o;
    o.x = f2b(v.x); o.y = f2b(v.y); o.z = f2b(v.z); o.w = f2b(v.w);
    *(ushort4*)(dst + blk * 512 + pos) = o;
}

// ---------- GEMM: C[M][N] = A[M][K] * B[N][K]^T, A/B in tiled format ----------
// 128x128 tile, BK=64. Staging: 1KB contiguous async_ld16 per wave-instr.
template <typename OUT>
__global__ void gemm_bt(const unsigned short* __restrict__ A,
                        const unsigned short* __restrict__ B,
                        OUT* __restrict__ C, int M, int N, int K) {
    __shared__ unsigned short As[16 * 512];   // slot s = x*2+kkb
    __shared__ unsigned short Bs[16 * 512];
    const int KB = K >> 5;                    // k-chunks per row-tile
    const int t = threadIdx.x;
    const int w = t >> 6;
    const int l = t & 63;
    const int lane15 = l & 15;
    const int quad = l >> 4;
    const int rowt = blockIdx.y * 8;          // row-tile index (16-row units)
    const int colt = blockIdx.x * 8;
    const int wm = (w >> 1) * 64;
    const int wn = (w & 1) * 64;

    const floatx4 vzero = {0.f, 0.f, 0.f, 0.f};
    floatx4 acc[4][4];
#pragma unroll
    for (int i = 0; i < 4; ++i)
#pragma unroll
        for (int j = 0; j < 4; ++j) acc[i][j] = vzero;

    const int xA = wm >> 4, xB = wn >> 4;
    for (int kc0 = 0; kc0 < KB; kc0 += 2) {
        __syncthreads();
#pragma unroll
        for (int j = 0; j < 4; ++j) {
            int s = w * 4 + j;
            int x = s >> 1, kkb = s & 1;
            size_t ablk = (size_t)(rowt + x) * KB + kc0 + kkb;
            size_t bblk = (size_t)(colt + x) * KB + kc0 + kkb;
            async_ld16(A + ablk * 512 + l * 8, As + s * 512 + l * 8);
            async_ld16(B + bblk * 512 + l * 8, Bs + s * 512 + l * 8);
        }
        __syncthreads();
#pragma unroll
        for (int kkb = 0; kkb < 2; ++kkb) {
            short8 af[4], bfr[4];
#pragma unroll
            for (int mi = 0; mi < 4; ++mi)
                af[mi] = *(const short8*)(As + ((xA + mi) * 2 + kkb) * 512 + l * 8);
#pragma unroll
            for (int ni = 0; ni < 4; ++ni)
                bfr[ni] = *(const short8*)(Bs + ((xB + ni) * 2 + kkb) * 512 + l * 8);
#pragma unroll
            for (int mi = 0; mi < 4; ++mi)
#pragma unroll
                for (int ni = 0; ni < 4; ++ni)
                    acc[mi][ni] = __builtin_amdgcn_mfma_f32_16x16x32_bf16(af[mi], bfr[ni], acc[mi][ni], 0, 0, 0);
        }
    }
#pragma unroll
    for (int mi = 0; mi < 4; ++mi)
#pragma unroll
        for (int ni = 0; ni < 4; ++ni)
#pragma unroll
            for (int r = 0; r < 4; ++r) {
                int m = rowt * 16 + wm + mi * 16 + quad * 4 + r;
                int n = colt * 16 + wn + ni * 16 + lane15;
                store_out(C, (size_t)m * N + n, acc[mi][ni][r]);
            }
}

// ---------- RoPE + split qkv -> Q [NH][S][HD] (pre-scaled), K, V [NKV][S][HD] ----------
__global__ void rope_split(const unsigned short* __restrict__ qkv,
                           unsigned short* __restrict__ Qd,
                           unsigned short* __restrict__ Kd,
                           unsigned short* __restrict__ Vd) {
    const int s = blockIdx.x;
    const int t = threadIdx.x;
    const unsigned short* row = qkv + (size_t)s * QKV_OUT;
    const float L2T_48 = 0.2768273412406135f;   // log2(10000)/48
    const float SCALE2 = 0.14724444f;           // (1/sqrt(96)) * log2(e)

    for (int i = t; i < NH * 48; i += 256) {
        int h = i / 48, d = i - (i / 48) * 48;
        float f = (float)s * exp2f(-(float)d * L2T_48);
        float sn, cs;
        sincosf(f, &sn, &cs);
        float q1 = b2f(row[h * 96 + d]);
        float q2 = b2f(row[h * 96 + d + 48]);
        size_t base = ((size_t)h * S_LEN + s) * HD;
        Qd[base + d] = f2b((q1 * cs - q2 * sn) * SCALE2);
        Qd[base + d + 48] = f2b((q2 * cs + q1 * sn) * SCALE2);
    }
    for (int i = t; i < NKV * 48; i += 256) {
        int h = i / 48, d = i - (i / 48) * 48;
        float f = (float)s * exp2f(-(float)d * L2T_48);
        float sn, cs;
        sincosf(f, &sn, &cs);
        float k1 = b2f(row[3072 + h * 96 + d]);
        float k2 = b2f(row[3072 + h * 96 + d + 48]);
        size_t base = ((size_t)h * S_LEN + s) * HD;
        Kd[base + d] = f2b(k1 * cs - k2 * sn);
        Kd[base + d + 48] = f2b(k2 * cs + k1 * sn);
    }
    for (int i = t; i < NKV * HD; i += 256) {
        int h = i / 96, d = i - (i / 96) * 96;
        Vd[((size_t)h * S_LEN + s) * HD + d] = row[3840 + i];
    }
}

// ---------- V [NKV][S][HD] -> Vt [NKV][HD][S], LDS-tiled ----------
__global__ void transpose_v(const unsigned short* __restrict__ V,
                            unsigned short* __restrict__ Vt) {
    __shared__ unsigned short T[96][72];
    const int kvh = blockIdx.x >> 5;
    const int s0 = (blockIdx.x & 31) * 64;
    const int t = threadIdx.x;
#pragma unroll
    for (int it = 0; it < 3; ++it) {
        int c = it * 256 + t;
        int r = c / 12, c8 = c - r * 12;
        short8 v = *(const short8*)(V + ((size_t)kvh * S_LEN + s0 + r) * HD + c8 * 8);
#pragma unroll
        for (int j = 0; j < 8; ++j) T[c8 * 8 + j][r] = (unsigned short)v[j];
    }
    __syncthreads();
#pragma unroll
    for (int it = 0; it < 3; ++it) {
        int c = it * 256 + t;
        int d = c >> 3, c8 = c & 7;
        short8 v;
#pragma unroll
        for (int j = 0; j < 8; ++j) v[j] = (short)T[d][c8 * 8 + j];
        *(short8*)(Vt + ((size_t)kvh * HD + d) * S_LEN + s0 + c8 * 8) = v;
    }
}

// ---------- Flash attention, fixed-max softmax; O written in TILED format ----------
#define ATTN_M0 8.0f
__global__ __launch_bounds__(256) void attn_fwd(const unsigned short* __restrict__ Q,
                                                const unsigned short* __restrict__ K,
                                                const unsigned short* __restrict__ Vt,
                                                unsigned short* __restrict__ O) {
    __shared__ unsigned short Qs[4 * 3 * 512];
    __shared__ unsigned short Ks[12 * 512];
    __shared__ unsigned short Vs[12 * 512];
    __shared__ unsigned short Ps[4][16 * 72];
    const int h = blockIdx.x;
    const int qt = (int)gridDim.y - 1 - blockIdx.y;  // LPT: longest first
    const int kvh = h >> 2;                          // N_REP = 4
    const int q0 = qt * 64;
    const int t = threadIdx.x, w = t >> 6, l = t & 63;
    const int lane15 = l & 15, quad = l >> 4;
    unsigned short* Pw = Ps[w];

    const unsigned short* Qg = Q + ((size_t)h * S_LEN + q0) * HD;
#pragma unroll
    for (int kkb = 0; kkb < 3; ++kkb)
        async_ld16(Qg + (w * 16 + lane15) * HD + kkb * 32 + quad * 8,
                   Qs + (w * 3 + kkb) * 512 + l * 8);

    int koff[3], voff0[3];
    long vofS[3];
#pragma unroll
    for (int j = 0; j < 3; ++j) {
        int c = w * 3 + j;
        int ct = c & 3, kkb = c >> 2;
        koff[j] = (ct * 16 + lane15) * HD + kkb * 32 + quad * 8;
        int nt = c % 6, kb2 = c / 6;
        vofS[j] = (long)(nt * 16 + lane15) * S_LEN + kb2 * 32 + quad * 8;
        voff0[j] = c * 512 + l * 8;
    }

    const floatx4 vzero = {0.f, 0.f, 0.f, 0.f};
    floatx4 accO[6];
#pragma unroll
    for (int nt = 0; nt < 6; ++nt) accO[nt] = vzero;
    float lsum[4] = {0.f, 0.f, 0.f, 0.f};

    const unsigned short* Kg = K + (size_t)kvh * S_LEN * HD;
    const unsigned short* Vg = Vt + (size_t)kvh * HD * S_LEN;
    const int qrow0 = q0 + w * 16 + quad * 4;

    for (int kt = 0; kt <= qt; ++kt) {
        const int k0 = kt * 64;
        __syncthreads();
#pragma unroll
        for (int j = 0; j < 3; ++j) {
            int c = w * 3 + j;
            async_ld16(Kg + (size_t)k0 * HD + koff[j], Ks + c * 512 + l * 8);
            async_ld16(Vg + k0 + vofS[j], Vs + voff0[j]);
        }
        __syncthreads();

        floatx4 accS[4];
#pragma unroll
        for (int ct = 0; ct < 4; ++ct) accS[ct] = vzero;
#pragma unroll
        for (int kkb = 0; kkb < 3; ++kkb) {
            short8 aq = *(const short8*)(Qs + (w * 3 + kkb) * 512 + l * 8);
#pragma unroll
            for (int ct = 0; ct < 4; ++ct) {
                short8 bk = *(const short8*)(Ks + (kkb * 4 + ct) * 512 + l * 8);
                accS[ct] = __builtin_amdgcn_mfma_f32_16x16x32_bf16(aq, bk, accS[ct], 0, 0, 0);
            }
        }

        if (kt < qt) {
#pragma unroll
            for (int ct = 0; ct < 4; ++ct)
#pragma unroll
                for (int r = 0; r < 4; ++r) {
                    float p = fast_exp2(accS[ct][r] - ATTN_M0);
                    lsum[r] += p;
                    Pw[(quad * 4 + r) * 72 + ct * 16 + lane15] = f2b(p);
                }
        } else {
#pragma unroll
            for (int ct = 0; ct < 4; ++ct) {
                int kcol = k0 + ct * 16 + lane15;
#pragma unroll
                for (int r = 0; r < 4; ++r) {
                    float s = (kcol <= qrow0 + r) ? accS[ct][r] - ATTN_M0 : -1.0e30f;
                    float p = fast_exp2(s);
                    lsum[r] += p;
                    Pw[(quad * 4 + r) * 72 + ct * 16 + lane15] = f2b(p);
                }
            }
        }

#pragma unroll
        for (int kb2 = 0; kb2 < 2; ++kb2) {
            short8 ap = *(const short8*)(Pw + lane15 * 72 + kb2 * 32 + quad * 8);
#pragma unroll
            for (int nt = 0; nt < 6; ++nt) {
                short8 bv = *(const short8*)(Vs + (kb2 * 6 + nt) * 512 + l * 8);
                accO[nt] = __builtin_amdgcn_mfma_f32_16x16x32_bf16(ap, bv, accO[nt], 0, 0, 0);
            }
        }
    }

    for (int off = 1; off < 16; off <<= 1)
#pragma unroll
        for (int r = 0; r < 4; ++r) lsum[r] += __shfl_xor(lsum[r], off, 64);
    float inv[4];
#pragma unroll
    for (int r = 0; r < 4; ++r) inv[r] = 1.f / lsum[r];
    const int srow0 = q0 + w * 16 + quad * 4;
    // write attn output in tiled format (feeds O GEMM as A operand)
#pragma unroll
    for (int nt = 0; nt < 6; ++nt) {
        int n = h * HD + nt * 16 + lane15;               // h*96 is a multiple of 32
        size_t base = ((size_t)(srow0 >> 4) * (HID_DIM >> 5) + (n >> 5)) * 512
                      + ((n & 31) >> 3) * 128 + (n & 7);
#pragma unroll
        for (int r = 0; r < 4; ++r) {
            int m15 = (srow0 + r) & 15;                  // = quad*4 + r
            O[base + m15 * 8] = f2b(accO[nt][r] * inv[r]);
        }
    }
}

// ---------- launcher ----------
extern "C" void kernel_launch(void* const* d_in, const int* in_sizes, int n_in,
                              void* d_out, int out_size, void* d_ws, size_t ws_size,
                              hipStream_t stream) {
    const float* hidden = (const float*)d_in[0];
    const float* qkv_w = (const float*)d_in[3];
    const float* o_w = (const float*)d_in[4];
    float* out = (float*)d_out;

    unsigned short* Xb = (unsigned short*)d_ws;                 // [2048][3072] tiled
    unsigned short* Wq = Xb + (size_t)S_LEN * HID_DIM;          // [4608][3072] tiled
    unsigned short* Wo = Wq + (size_t)QKV_OUT * HID_DIM;        // [3072][3072] tiled
    unsigned short* QKVb = Wo + (size_t)HID_DIM * HID_DIM;      // [2048][4608] row-major
    unsigned short* Qb = QKVb + (size_t)S_LEN * QKV_OUT;        // [32][2048][96]
    unsigned short* Kb = Qb + (size_t)NH * S_LEN * HD;          // [8][2048][96]
    unsigned short* Vb = Kb + (size_t)NKV * S_LEN * HD;         // [8][2048][96]
    unsigned short* Ab = Vb + (size_t)NKV * S_LEN * HD;         // [2048][3072] tiled
    unsigned short* Vtb = QKVb;  // V^T [8][96][2048]; QKVb dead after rope_split

    int n1 = S_LEN * HID_DIM / 4, n2 = QKV_OUT * HID_DIM / 4, n3 = HID_DIM * HID_DIM / 4;
    int ntot = n1 + n2 + n3;
    cvt3_tiled<<<(ntot + 255) / 256, 256, 0, stream>>>(
        (const float4*)hidden, n1, (const float4*)qkv_w, n2, (const float4*)o_w, n3,
        Xb, Wq, Wo);

    gemm_bt<unsigned short><<<dim3(QKV_OUT / 128, S_LEN / 128), 256, 0, stream>>>(
        Xb, Wq, QKVb, S_LEN, QKV_OUT, HID_DIM);
    rope_split<<<S_LEN, 256, 0, stream>>>(QKVb, Qb, Kb, Vb);
    transpose_v<<<NKV * (S_LEN / 64), 256, 0, stream>>>(Vb, Vtb);
    attn_fwd<<<dim3(NH, S_LEN / 64), 256, 0, stream>>>(Qb, Kb, Vtb, Ab);
    gemm_bt<float><<<dim3(HID_DIM / 128, S_LEN / 128), 256, 0, stream>>>(
        Ab, Wo, out, S_LEN, HID_DIM, HID_DIM);
}

// Round 7
// 346.429 us; speedup vs baseline: 1.3499x; 1.0846x over previous
//
#include <hip/hip_runtime.h>

#define S_LEN 2048
#define HID_DIM 3072
#define NH 32
#define NKV 8
#define HD 96
#define QKV_OUT 4608  // NH*HD + 2*NKV*HD

typedef __attribute__((ext_vector_type(8))) short short8;
typedef __attribute__((ext_vector_type(4))) float floatx4;

// ---------- helpers ----------
__device__ __forceinline__ unsigned short f2b(float f) {
    unsigned int u = __float_as_uint(f);
    u = (u + 0x7FFFu + ((u >> 16) & 1u)) >> 16;   // RNE
    return (unsigned short)u;
}
__device__ __forceinline__ float b2f(unsigned short h) {
    return __uint_as_float(((unsigned int)h) << 16);
}
__device__ __forceinline__ void async_ld16(const void* g, void* l) {
    __builtin_amdgcn_global_load_lds((const __attribute__((address_space(1))) void*)g,
                                     (__attribute__((address_space(3))) void*)l, 16, 0, 0);
}
__device__ __forceinline__ float fast_exp2(float x) {
#if __has_builtin(__builtin_amdgcn_exp2f)
    return __builtin_amdgcn_exp2f(x);   // v_exp_f32
#else
    return exp2f(x);
#endif
}
__device__ __forceinline__ void store_out(float* C, size_t i, float v) { C[i] = v; }
__device__ __forceinline__ void store_out(unsigned short* C, size_t i, float v) { C[i] = f2b(v); }

// ===================== MFMA-fragment-tiled global format =====================
// Matrix [R][K] (K multiple of 32, R multiple of 16) stored as 512-short blocks:
//   blk = (r>>4)*(K>>5) + (k>>5)
//   pos = ((k&31)>>3)*128 + (r&15)*8 + (k&7)
// Block == exact wave lane order for MFMA A/B fragments (lane l=q*16+i holds
// elements (i, q*8+j)): staging is ONE contiguous 1KB async_ld16 per wave AND
// LDS reads are ds_read_b128 at base+lane*16 (conflict-free).

// ---------- f32 row-major -> bf16 tiled, one 512-block per wave ----------
// Lane reads the exact 8 floats of its fragment (2x float4), writes short8 at
// base + l*16B -> the wave store is one contiguous 1KB segment (R5's scattered
// ushort4 stores caused 2x write amplification).
__global__ void cvt3_tiled(const float* __restrict__ a, int nab,
                           const float* __restrict__ b, int nbb,
                           const float* __restrict__ c, int ncb,
                           unsigned short* __restrict__ oa,
                           unsigned short* __restrict__ ob,
                           unsigned short* __restrict__ oc) {
    int wid = blockIdx.x * 4 + (threadIdx.x >> 6);   // global wave id = tile-block id
    const int l = threadIdx.x & 63;
    const float* src;
    unsigned short* dst;
    int j = wid;
    if (j < nab) { src = a; dst = oa; }
    else {
        j -= nab;
        if (j < nbb) { src = b; dst = ob; }
        else {
            j -= nbb;
            if (j >= ncb) return;
            src = c; dst = oc;
        }
    }
    const int KB = HID_DIM >> 5;                     // 96 k-chunks per row-tile
    int rt = j / KB, kc = j - rt * KB;
    int i = l & 15, q = l >> 4;
    const float* p = src + ((size_t)rt * 16 + i) * HID_DIM + kc * 32 + q * 8;
    float4 v0 = *(const float4*)p;
    float4 v1 = *(const float4*)(p + 4);
    short8 o;
    o[0] = (short)f2b(v0.x); o[1] = (short)f2b(v0.y);
    o[2] = (short)f2b(v0.z); o[3] = (short)f2b(v0.w);
    o[4] = (short)f2b(v1.x); o[5] = (short)f2b(v1.y);
    o[6] = (short)f2b(v1.z); o[7] = (short)f2b(v1.w);
    *(short8*)(dst + (size_t)j * 512 + l * 8) = o;
}

// ---------- GEMM: C[M][N] = A[M][K] * B[N][K]^T, A/B in tiled format ----------
// 128x128 tile, BK=64. Staging: 1KB contiguous async_ld16 per wave-instr.
template <typename OUT>
__global__ void gemm_bt(const unsigned short* __restrict__ A,
                        const unsigned short* __restrict__ B,
                        OUT* __restrict__ C, int M, int N, int K) {
    __shared__ unsigned short As[16 * 512];   // slot s = x*2+kkb
    __shared__ unsigned short Bs[16 * 512];
    const int KB = K >> 5;                    // k-chunks per row-tile
    const int t = threadIdx.x;
    const int w = t >> 6;
    const int l = t & 63;
    const int lane15 = l & 15;
    const int quad = l >> 4;
    const int rowt = blockIdx.y * 8;          // row-tile index (16-row units)
    const int colt = blockIdx.x * 8;
    const int wm = (w >> 1) * 64;
    const int wn = (w & 1) * 64;

    const floatx4 vzero = {0.f, 0.f, 0.f, 0.f};
    floatx4 acc[4][4];
#pragma unroll
    for (int i = 0; i < 4; ++i)
#pragma unroll
        for (int j = 0; j < 4; ++j) acc[i][j] = vzero;

    const int xA = wm >> 4, xB = wn >> 4;
    for (int kc0 = 0; kc0 < KB; kc0 += 2) {
        __syncthreads();
#pragma unroll
        for (int j = 0; j < 4; ++j) {
            int s = w * 4 + j;
            int x = s >> 1, kkb = s & 1;
            size_t ablk = (size_t)(rowt + x) * KB + kc0 + kkb;
            size_t bblk = (size_t)(colt + x) * KB + kc0 + kkb;
            async_ld16(A + ablk * 512 + l * 8, As + s * 512 + l * 8);
            async_ld16(B + bblk * 512 + l * 8, Bs + s * 512 + l * 8);
        }
        __syncthreads();
#pragma unroll
        for (int kkb = 0; kkb < 2; ++kkb) {
            short8 af[4], bfr[4];
#pragma unroll
            for (int mi = 0; mi < 4; ++mi)
                af[mi] = *(const short8*)(As + ((xA + mi) * 2 + kkb) * 512 + l * 8);
#pragma unroll
            for (int ni = 0; ni < 4; ++ni)
                bfr[ni] = *(const short8*)(Bs + ((xB + ni) * 2 + kkb) * 512 + l * 8);
#pragma unroll
            for (int mi = 0; mi < 4; ++mi)
#pragma unroll
                for (int ni = 0; ni < 4; ++ni)
                    acc[mi][ni] = __builtin_amdgcn_mfma_f32_16x16x32_bf16(af[mi], bfr[ni], acc[mi][ni], 0, 0, 0);
        }
    }
#pragma unroll
    for (int mi = 0; mi < 4; ++mi)
#pragma unroll
        for (int ni = 0; ni < 4; ++ni)
#pragma unroll
            for (int r = 0; r < 4; ++r) {
                int m = rowt * 16 + wm + mi * 16 + quad * 4 + r;
                int n = colt * 16 + wn + ni * 16 + lane15;
                store_out(C, (size_t)m * N + n, acc[mi][ni][r]);
            }
}

// ---------- RoPE + split qkv -> Q [NH][S][HD] (pre-scaled), K, V [NKV][S][HD] ----------
__global__ void rope_split(const unsigned short* __restrict__ qkv,
                           unsigned short* __restrict__ Qd,
                           unsigned short* __restrict__ Kd,
                           unsigned short* __restrict__ Vd) {
    const int s = blockIdx.x;
    const int t = threadIdx.x;
    const unsigned short* row = qkv + (size_t)s * QKV_OUT;
    const float L2T_48 = 0.2768273412406135f;   // log2(10000)/48
    const float SCALE2 = 0.14724444f;           // (1/sqrt(96)) * log2(e)

    for (int i = t; i < NH * 48; i += 256) {
        int h = i / 48, d = i - (i / 48) * 48;
        float f = (float)s * exp2f(-(float)d * L2T_48);
        float sn, cs;
        sincosf(f, &sn, &cs);
        float q1 = b2f(row[h * 96 + d]);
        float q2 = b2f(row[h * 96 + d + 48]);
        size_t base = ((size_t)h * S_LEN + s) * HD;
        Qd[base + d] = f2b((q1 * cs - q2 * sn) * SCALE2);
        Qd[base + d + 48] = f2b((q2 * cs + q1 * sn) * SCALE2);
    }
    for (int i = t; i < NKV * 48; i += 256) {
        int h = i / 48, d = i - (i / 48) * 48;
        float f = (float)s * exp2f(-(float)d * L2T_48);
        float sn, cs;
        sincosf(f, &sn, &cs);
        float k1 = b2f(row[3072 + h * 96 + d]);
        float k2 = b2f(row[3072 + h * 96 + d + 48]);
        size_t base = ((size_t)h * S_LEN + s) * HD;
        Kd[base + d] = f2b(k1 * cs - k2 * sn);
        Kd[base + d + 48] = f2b(k2 * cs + k1 * sn);
    }
    for (int i = t; i < NKV * HD; i += 256) {
        int h = i / 96, d = i - (i / 96) * 96;
        Vd[((size_t)h * S_LEN + s) * HD + d] = row[3840 + i];
    }
}

// ---------- V [NKV][S][HD] -> Vt [NKV][HD][S], LDS-tiled ----------
__global__ void transpose_v(const unsigned short* __restrict__ V,
                            unsigned short* __restrict__ Vt) {
    __shared__ unsigned short T[96][72];
    const int kvh = blockIdx.x >> 5;
    const int s0 = (blockIdx.x & 31) * 64;
    const int t = threadIdx.x;
#pragma unroll
    for (int it = 0; it < 3; ++it) {
        int c = it * 256 + t;
        int r = c / 12, c8 = c - r * 12;
        short8 v = *(const short8*)(V + ((size_t)kvh * S_LEN + s0 + r) * HD + c8 * 8);
#pragma unroll
        for (int j = 0; j < 8; ++j) T[c8 * 8 + j][r] = (unsigned short)v[j];
    }
    __syncthreads();
#pragma unroll
    for (int it = 0; it < 3; ++it) {
        int c = it * 256 + t;
        int d = c >> 3, c8 = c & 7;
        short8 v;
#pragma unroll
        for (int j = 0; j < 8; ++j) v[j] = (short)T[d][c8 * 8 + j];
        *(short8*)(Vt + ((size_t)kvh * HD + d) * S_LEN + s0 + c8 * 8) = v;
    }
}

// ---------- Flash attention, fixed-max softmax; O written in TILED format ----------
#define ATTN_M0 8.0f
__global__ __launch_bounds__(256) void attn_fwd(const unsigned short* __restrict__ Q,
                                                const unsigned short* __restrict__ K,
                                                const unsigned short* __restrict__ Vt,
                                                unsigned short* __restrict__ O) {
    __shared__ unsigned short Qs[4 * 3 * 512];
    __shared__ unsigned short Ks[12 * 512];
    __shared__ unsigned short Vs[12 * 512];
    __shared__ unsigned short Ps[4][16 * 72];
    const int h = blockIdx.x;
    const int qt = (int)gridDim.y - 1 - blockIdx.y;  // LPT: longest first
    const int kvh = h >> 2;                          // N_REP = 4
    const int q0 = qt * 64;
    const int t = threadIdx.x, w = t >> 6, l = t & 63;
    const int lane15 = l & 15, quad = l >> 4;
    unsigned short* Pw = Ps[w];

    const unsigned short* Qg = Q + ((size_t)h * S_LEN + q0) * HD;
#pragma unroll
    for (int kkb = 0; kkb < 3; ++kkb)
        async_ld16(Qg + (w * 16 + lane15) * HD + kkb * 32 + quad * 8,
                   Qs + (w * 3 + kkb) * 512 + l * 8);

    int koff[3], voff0[3];
    long vofS[3];
#pragma unroll
    for (int j = 0; j < 3; ++j) {
        int c = w * 3 + j;
        int ct = c & 3, kkb = c >> 2;
        koff[j] = (ct * 16 + lane15) * HD + kkb * 32 + quad * 8;
        int nt = c % 6, kb2 = c / 6;
        vofS[j] = (long)(nt * 16 + lane15) * S_LEN + kb2 * 32 + quad * 8;
        voff0[j] = c * 512 + l * 8;
    }

    const floatx4 vzero = {0.f, 0.f, 0.f, 0.f};
    floatx4 accO[6];
#pragma unroll
    for (int nt = 0; nt < 6; ++nt) accO[nt] = vzero;
    float lsum[4] = {0.f, 0.f, 0.f, 0.f};

    const unsigned short* Kg = K + (size_t)kvh * S_LEN * HD;
    const unsigned short* Vg = Vt + (size_t)kvh * HD * S_LEN;
    const int qrow0 = q0 + w * 16 + quad * 4;

    for (int kt = 0; kt <= qt; ++kt) {
        const int k0 = kt * 64;
        __syncthreads();
#pragma unroll
        for (int j = 0; j < 3; ++j) {
            int c = w * 3 + j;
            async_ld16(Kg + (size_t)k0 * HD + koff[j], Ks + c * 512 + l * 8);
            async_ld16(Vg + k0 + vofS[j], Vs + voff0[j]);
        }
        __syncthreads();

        floatx4 accS[4];
#pragma unroll
        for (int ct = 0; ct < 4; ++ct) accS[ct] = vzero;
#pragma unroll
        for (int kkb = 0; kkb < 3; ++kkb) {
            short8 aq = *(const short8*)(Qs + (w * 3 + kkb) * 512 + l * 8);
#pragma unroll
            for (int ct = 0; ct < 4; ++ct) {
                short8 bk = *(const short8*)(Ks + (kkb * 4 + ct) * 512 + l * 8);
                accS[ct] = __builtin_amdgcn_mfma_f32_16x16x32_bf16(aq, bk, accS[ct], 0, 0, 0);
            }
        }

        if (kt < qt) {
#pragma unroll
            for (int ct = 0; ct < 4; ++ct)
#pragma unroll
                for (int r = 0; r < 4; ++r) {
                    float p = fast_exp2(accS[ct][r] - ATTN_M0);
                    lsum[r] += p;
                    Pw[(quad * 4 + r) * 72 + ct * 16 + lane15] = f2b(p);
                }
        } else {
#pragma unroll
            for (int ct = 0; ct < 4; ++ct) {
                int kcol = k0 + ct * 16 + lane15;
#pragma unroll
                for (int r = 0; r < 4; ++r) {
                    float s = (kcol <= qrow0 + r) ? accS[ct][r] - ATTN_M0 : -1.0e30f;
                    float p = fast_exp2(s);
                    lsum[r] += p;
                    Pw[(quad * 4 + r) * 72 + ct * 16 + lane15] = f2b(p);
                }
            }
        }

#pragma unroll
        for (int kb2 = 0; kb2 < 2; ++kb2) {
            short8 ap = *(const short8*)(Pw + lane15 * 72 + kb2 * 32 + quad * 8);
#pragma unroll
            for (int nt = 0; nt < 6; ++nt) {
                short8 bv = *(const short8*)(Vs + (kb2 * 6 + nt) * 512 + l * 8);
                accO[nt] = __builtin_amdgcn_mfma_f32_16x16x32_bf16(ap, bv, accO[nt], 0, 0, 0);
            }
        }
    }

    for (int off = 1; off < 16; off <<= 1)
#pragma unroll
        for (int r = 0; r < 4; ++r) lsum[r] += __shfl_xor(lsum[r], off, 64);
    float inv[4];
#pragma unroll
    for (int r = 0; r < 4; ++r) inv[r] = 1.f / lsum[r];
    const int srow0 = q0 + w * 16 + quad * 4;
    // write attn output in tiled format (feeds O GEMM as A operand)
#pragma unroll
    for (int nt = 0; nt < 6; ++nt) {
        int n = h * HD + nt * 16 + lane15;               // h*96 is a multiple of 32
        size_t base = ((size_t)(srow0 >> 4) * (HID_DIM >> 5) + (n >> 5)) * 512
                      + ((n & 31) >> 3) * 128 + (n & 7);
#pragma unroll
        for (int r = 0; r < 4; ++r) {
            int m15 = (srow0 + r) & 15;                  // = quad*4 + r
            O[base + m15 * 8] = f2b(accO[nt][r] * inv[r]);
        }
    }
}

// ---------- launcher ----------
extern "C" void kernel_launch(void* const* d_in, const int* in_sizes, int n_in,
                              void* d_out, int out_size, void* d_ws, size_t ws_size,
                              hipStream_t stream) {
    const float* hidden = (const float*)d_in[0];
    const float* qkv_w = (const float*)d_in[3];
    const float* o_w = (const float*)d_in[4];
    float* out = (float*)d_out;

    unsigned short* Xb = (unsigned short*)d_ws;                 // [2048][3072] tiled
    unsigned short* Wq = Xb + (size_t)S_LEN * HID_DIM;          // [4608][3072] tiled
    unsigned short* Wo = Wq + (size_t)QKV_OUT * HID_DIM;        // [3072][3072] tiled
    unsigned short* QKVb = Wo + (size_t)HID_DIM * HID_DIM;      // [2048][4608] row-major
    unsigned short* Qb = QKVb + (size_t)S_LEN * QKV_OUT;        // [32][2048][96]
    unsigned short* Kb = Qb + (size_t)NH * S_LEN * HD;          // [8][2048][96]
    unsigned short* Vb = Kb + (size_t)NKV * S_LEN * HD;         // [8][2048][96]
    unsigned short* Ab = Vb + (size_t)NKV * S_LEN * HD;         // [2048][3072] tiled
    unsigned short* Vtb = QKVb;  // V^T [8][96][2048]; QKVb dead after rope_split

    // tile-block counts (512 elements each)
    int nab = S_LEN * HID_DIM / 512, nbb = QKV_OUT * HID_DIM / 512, ncb = HID_DIM * HID_DIM / 512;
    int nblk = nab + nbb + ncb;   // 58368, divisible by 4
    cvt3_tiled<<<nblk / 4, 256, 0, stream>>>(hidden, nab, qkv_w, nbb, o_w, ncb, Xb, Wq, Wo);

    gemm_bt<unsigned short><<<dim3(QKV_OUT / 128, S_LEN / 128), 256, 0, stream>>>(
        Xb, Wq, QKVb, S_LEN, QKV_OUT, HID_DIM);
    rope_split<<<S_LEN, 256, 0, stream>>>(QKVb, Qb, Kb, Vb);
    transpose_v<<<NKV * (S_LEN / 64), 256, 0, stream>>>(Vb, Vtb);
    attn_fwd<<<dim3(NH, S_LEN / 64), 256, 0, stream>>>(Qb, Kb, Vtb, Ab);
    gemm_bt<float><<<dim3(HID_DIM / 128, S_LEN / 128), 256, 0, stream>>>(
        Ab, Wo, out, S_LEN, HID_DIM, HID_DIM);
}